// Round 11
// baseline (524.941 us; speedup 1.0000x reference)
//
#include <hip/hip_runtime.h>

#define KITER 10
#define TILE 4096
#define BCAP 16384  // bucket staging capacity (expected 8192/bucket, +90 sigma)
typedef unsigned short bf16_t;
typedef __attribute__((ext_vector_type(4))) short bf16x4;
typedef __attribute__((ext_vector_type(8))) short bf16x8;
typedef __attribute__((ext_vector_type(4))) float f32x4;

__device__ __forceinline__ float bf2f(bf16_t u) {
  union { unsigned u; float f; } cv;
  cv.u = ((unsigned)u) << 16;
  return cv.f;
}
__device__ __forceinline__ bf16_t f2bf(float f) {
  unsigned u = __float_as_uint(f);
  unsigned r = (u + 0x7FFFu + ((u >> 16) & 1u)) >> 16;  // round-nearest-even
  return (bf16_t)r;
}

// ---------------- bucket cursor init: bcur[b] = b*BCAP ----------------
__global__ void k_initb(int* __restrict__ bcur, int nbuck) {
  int i = threadIdx.x;
  if (i < nbuck) bcur[i] = i * BCAP;
}

// ---------------- bucket sort pass A: tile -> per-bucket coalesced runs ------
__global__ __launch_bounds__(256) void k_bucket(const int* __restrict__ ei, int E,
                                                int* __restrict__ bcur,
                                                int2* __restrict__ barr) {
  __shared__ int hist[256];
  __shared__ int scn[256];
  __shared__ int excl[256];
  __shared__ int gb[256];
  __shared__ unsigned char lb[TILE];
  __shared__ int2 stg[TILE];
  int t = threadIdx.x;
  int base = blockIdx.x * TILE;
  hist[t] = 0;
  __syncthreads();
  int s[16], c[16];
#pragma unroll
  for (int i = 0; i < 16; ++i) {
    int e = base + i * 256 + t;
    if (e < E) {
      s[i] = ei[e];
      c[i] = ei[E + e];
      atomicAdd(&hist[c[i] >> 9], 1);
    } else {
      c[i] = -1;
    }
  }
  __syncthreads();
  int h = hist[t];
  scn[t] = h;
  __syncthreads();
  for (int off = 1; off < 256; off <<= 1) {
    int v = (t >= off) ? scn[t - off] : 0;
    __syncthreads();
    scn[t] += v;
    __syncthreads();
  }
  excl[t] = scn[t] - h;
  gb[t] = (h > 0) ? atomicAdd(&bcur[t], h) : 0;
  __syncthreads();
  hist[t] = excl[t];  // reuse as local placement cursor
  __syncthreads();
#pragma unroll
  for (int i = 0; i < 16; ++i) {
    if (c[i] >= 0) {
      int b = c[i] >> 9;
      int p = atomicAdd(&hist[b], 1);
      stg[p] = make_int2(s[i], c[i]);
      lb[p] = (unsigned char)b;
    }
  }
  __syncthreads();
  int cntE = min(TILE, E - base);
#pragma unroll
  for (int i = 0; i < 16; ++i) {
    int p = i * 256 + t;
    if (p < cntE) {
      int b = lb[p];
      barr[gb[b] + (p - excl[b])] = stg[p];
    }
  }
}

// ---------------- bucket-level exclusive prefix (nbuck <= 256), 1 block ------
__global__ void k_bscan(const int* __restrict__ bcur, int* __restrict__ bstart,
                        int nbuck, int* __restrict__ rowptr, int N, int E) {
  __shared__ int s[256];
  int t = threadIdx.x;
  int v = (t < nbuck) ? (bcur[t] - t * BCAP) : 0;
  s[t] = v;
  __syncthreads();
  for (int off = 1; off < 256; off <<= 1) {
    int tv = (t >= off) ? s[t - off] : 0;
    __syncthreads();
    s[t] += tv;
    __syncthreads();
  }
  if (t < nbuck) bstart[t] = s[t] - v;
  if (t == 0) rowptr[N] = E;
}

// ---------------- pass B: bucket -> CSR; also emits rowptr & dinv ------------
__global__ __launch_bounds__(512) void k_finalize(const int* __restrict__ bcur,
                                                  const int* __restrict__ bstart,
                                                  const int2* __restrict__ barr,
                                                  int* __restrict__ rowptr,
                                                  float* __restrict__ dinv,
                                                  int* __restrict__ ed4, int N) {
  __shared__ int cnt[512];
  __shared__ int sbuf[512];
  __shared__ int cur[512];
  int b = blockIdx.x;
  int node0 = b << 9;
  int nn = min(512, N - node0);
  int t = threadIdx.x;
  cnt[t] = 0;
  __syncthreads();
  int m = bcur[b] - b * BCAP;  // edges in this bucket
  int src = b * BCAP;
  int bst = bstart[b];
  for (int i = t; i < m; i += 512) atomicAdd(&cnt[barr[src + i].y - node0], 1);
  __syncthreads();
  int v = cnt[t];
  sbuf[t] = v;
  __syncthreads();
  for (int off = 1; off < 512; off <<= 1) {
    int tv = (t >= off) ? sbuf[t - off] : 0;
    __syncthreads();
    sbuf[t] += tv;
    __syncthreads();
  }
  int excl = sbuf[t] - v;
  if (t < nn) {
    rowptr[node0 + t] = bst + excl;
    dinv[node0 + t] = rsqrtf((float)v + 1.0f);
  }
  cur[t] = bst + excl;
  __syncthreads();
  for (int i = t; i < m; i += 512) {
    int2 q = barr[src + i];
    int slot = atomicAdd(&cur[q.y - node0], 1);
    ed4[slot] = q.x;
  }
}

// ---------------- W pack: split fp32 W into bf16 hi/lo, MFMA B-frag layout ----
__global__ void k_prep_w(const float* __restrict__ W, short* __restrict__ Whp,
                         short* __restrict__ Wlp) {
  int i = blockIdx.x * 256 + threadIdx.x;  // 0..16383
  int j = i & 7;
  int lane = (i >> 3) & 63;
  int cg = (i >> 9) & 3;
  int kc = i >> 11;
  int k = kc * 32 + (lane >> 4) * 8 + j;
  int col = cg * 16 + (lane & 15);
  float w = W[k * 64 + col];
  unsigned u = __float_as_uint(w);
  unsigned hbits = u & 0xFFFF0000u;  // truncate: residual captured exactly by lo
  Whp[i] = (short)(hbits >> 16);
  Wlp[i] = (short)f2bf(w - __uint_as_float(hbits));
}

// ---------------- h = relu(x @ W1 + b1), split-precision bf16 MFMA -----------
// Measured-best R5 structure. Epilogue now writes hb/zs0 in QUARTER-MAJOR
// layout [4][N][16] (bf16): thread t owns (row, quarter cq=t&3) so the two
// 16 B stores per array remain contiguous 32 B runs. h (fp32) stays [N][64].
__global__ __launch_bounds__(512) void k_gemm_mfma(const float* __restrict__ x,
                                                   const short* __restrict__ Whp,
                                                   const short* __restrict__ Wlp,
                                                   const float* __restrict__ b,
                                                   const float* __restrict__ dinv,
                                                   float* __restrict__ h,
                                                   bf16_t* __restrict__ hbq,
                                                   bf16_t* __restrict__ zs0q, int N) {
  __shared__ __align__(16) char smem[65536];
  short* WhS = (short*)smem;             // 32 KB
  short* WlS = (short*)(smem + 32768);   // 32 KB
  float* Cst = (float*)smem;             // reused post-compute: 128 x 68 floats
  int tid = threadIdx.x;
  for (int i = tid; i < 2048; i += 512) {
    ((int4*)WhS)[i] = ((const int4*)Whp)[i];
    ((int4*)WlS)[i] = ((const int4*)Wlp)[i];
  }
  __syncthreads();
  int wid = tid >> 6;
  int lane = tid & 63;
  int rr = lane & 15;
  int q = lane >> 4;
  long row0 = (long)blockIdx.x * 128 + wid * 16;
  long arow = row0 + rr;
  if (arow > N - 1) arow = N - 1;  // clamp (stores guarded)
  const float* xr = x + arow * 256 + q * 8;

  // prefetch whole row slice: 8 kchunks x 8 floats
  f32x4 xa[8], xb[8];
#pragma unroll
  for (int kc = 0; kc < 8; ++kc) {
    xa[kc] = *(const f32x4*)(xr + kc * 32);
    xb[kc] = *(const f32x4*)(xr + kc * 32 + 4);
  }

  f32x4 acc[4];
#pragma unroll
  for (int cg = 0; cg < 4; ++cg) acc[cg] = (f32x4){0.f, 0.f, 0.f, 0.f};

#pragma unroll
  for (int kc = 0; kc < 8; ++kc) {
    float f[8] = {xa[kc].x, xa[kc].y, xa[kc].z, xa[kc].w,
                  xb[kc].x, xb[kc].y, xb[kc].z, xb[kc].w};
    bf16x8 xh, xl;
#pragma unroll
    for (int j = 0; j < 8; ++j) {
      unsigned u = __float_as_uint(f[j]);
      unsigned hbits = u & 0xFFFF0000u;
      xh[j] = (short)(hbits >> 16);
      xl[j] = (short)f2bf(f[j] - __uint_as_float(hbits));
    }
#pragma unroll
    for (int cg = 0; cg < 4; ++cg) {
      const bf16x8 wh = *(const bf16x8*)&WhS[((kc * 4 + cg) * 64 + lane) * 8];
      const bf16x8 wl = *(const bf16x8*)&WlS[((kc * 4 + cg) * 64 + lane) * 8];
      acc[cg] = __builtin_amdgcn_mfma_f32_16x16x32_bf16(xh, wh, acc[cg], 0, 0, 0);
      acc[cg] = __builtin_amdgcn_mfma_f32_16x16x32_bf16(xl, wh, acc[cg], 0, 0, 0);
      acc[cg] = __builtin_amdgcn_mfma_f32_16x16x32_bf16(xh, wl, acc[cg], 0, 0, 0);
    }
  }

  // -------- epilogue: bias+relu in-reg, stage C tile to LDS (W is dead) -----
  __syncthreads();  // all waves finished reading WhS/WlS
#pragma unroll
  for (int cg = 0; cg < 4; ++cg) {
    float bias = b[cg * 16 + rr];
#pragma unroll
    for (int r = 0; r < 4; ++r) {
      float v = fmaxf(acc[cg][r] + bias, 0.f);
      Cst[(wid * 16 + q * 4 + r) * 68 + cg * 16 + rr] = v;
    }
  }
  __syncthreads();

  // -------- coalesced writeout: thread t -> row t>>2, col quarter t&3 -------
  int lrow = tid >> 2;
  int cq = tid & 3;
  long grow = (long)blockIdx.x * 128 + lrow;
  if (grow < N) {
    union F4U { f32x4 v; float f[4]; };
    const float* cp = &Cst[lrow * 68 + cq * 16];
    F4U w0, w1, w2, w3;
    w0.v = *(const f32x4*)cp;
    w1.v = *(const f32x4*)(cp + 4);
    w2.v = *(const f32x4*)(cp + 8);
    w3.v = *(const f32x4*)(cp + 12);
    size_t ob = (size_t)grow * 64 + cq * 16;
    float* hp = h + ob;
    *(f32x4*)hp = w0.v;
    *(f32x4*)(hp + 4) = w1.v;
    *(f32x4*)(hp + 8) = w2.v;
    *(f32x4*)(hp + 12) = w3.v;
    float dv = dinv[grow];
    uint4 ub, ub2, uz, uz2;
    ub.x = (unsigned)f2bf(w0.f[0]) | ((unsigned)f2bf(w0.f[1]) << 16);
    ub.y = (unsigned)f2bf(w0.f[2]) | ((unsigned)f2bf(w0.f[3]) << 16);
    ub.z = (unsigned)f2bf(w1.f[0]) | ((unsigned)f2bf(w1.f[1]) << 16);
    ub.w = (unsigned)f2bf(w1.f[2]) | ((unsigned)f2bf(w1.f[3]) << 16);
    ub2.x = (unsigned)f2bf(w2.f[0]) | ((unsigned)f2bf(w2.f[1]) << 16);
    ub2.y = (unsigned)f2bf(w2.f[2]) | ((unsigned)f2bf(w2.f[3]) << 16);
    ub2.z = (unsigned)f2bf(w3.f[0]) | ((unsigned)f2bf(w3.f[1]) << 16);
    ub2.w = (unsigned)f2bf(w3.f[2]) | ((unsigned)f2bf(w3.f[3]) << 16);
    uz.x = (unsigned)f2bf(dv * w0.f[0]) | ((unsigned)f2bf(dv * w0.f[1]) << 16);
    uz.y = (unsigned)f2bf(dv * w0.f[2]) | ((unsigned)f2bf(dv * w0.f[3]) << 16);
    uz.z = (unsigned)f2bf(dv * w1.f[0]) | ((unsigned)f2bf(dv * w1.f[1]) << 16);
    uz.w = (unsigned)f2bf(dv * w1.f[2]) | ((unsigned)f2bf(dv * w1.f[3]) << 16);
    uz2.x = (unsigned)f2bf(dv * w2.f[0]) | ((unsigned)f2bf(dv * w2.f[1]) << 16);
    uz2.y = (unsigned)f2bf(dv * w2.f[2]) | ((unsigned)f2bf(dv * w2.f[3]) << 16);
    uz2.z = (unsigned)f2bf(dv * w3.f[0]) | ((unsigned)f2bf(dv * w3.f[1]) << 16);
    uz2.w = (unsigned)f2bf(dv * w3.f[2]) | ((unsigned)f2bf(dv * w3.f[3]) << 16);
    // quarter-major: [cq][node][16ch] (bf16) -> 32 B contiguous per thread
    size_t oq = (size_t)cq * (size_t)N * 16 + (size_t)grow * 16;
    *(uint4*)(hbq + oq) = ub;
    *(uint4*)(hbq + oq + 8) = ub2;
    *(uint4*)(zs0q + oq) = uz;
    *(uint4*)(zs0q + oq + 8) = uz2;
  }
}

// ---------------- propagation: channel-quarter passes, XCD-localized ---------
// z state is quarter-major zq[4][N][16] bf16: one quarter = 3.2 MB < 4 MB
// per-XCD L2. Grid = pairs*8 blocks; with round-robin blockIdx->XCD mapping,
// quarter = (blockIdx&7)>>1 pins each quarter to ONE XCD PAIR for all 10
// iterations, so gathers hit that XCD's L2 instead of L3 (working set was
// 12.8 MB = 3.2x L2 before). 4 lanes/node-group (4 ch each), 16 nodes/wave;
// ed4 index prefetch kept from R10. Falls back gracefully (correctness
// independent of XCD mapping).
template <int LAST>
__global__ __launch_bounds__(256) void k_propq(const int* __restrict__ rowptr,
                                               const int* __restrict__ ed4,
                                               const float* __restrict__ dinv,
                                               const bf16_t* __restrict__ zq,
                                               const bf16_t* __restrict__ hbq,
                                               const float* __restrict__ hf,
                                               void* __restrict__ zout_, int N,
                                               int pairs) {
  int tid = threadIdx.x;
  int lane = tid & 63;
  int u = lane & 3;        // channel slot: channels qr*16 + u*4 .. +3
  int g = lane >> 2;       // node sub-index within wave (0..15)
  int gbase = lane & 60;   // first lane of this 4-lane group
  int b = blockIdx.x;
  int xcd = b & 7;
  int qr = xcd >> 1;       // quarter pinned to XCD pair
  int sub = xcd & 1;
  int seg = (b >> 3) * 2 + sub;  // 64-node segment
  int node = seg * 64 + (tid >> 6) * 16 + g;
  bool live = node < N;
  if (!live) node = N - 1;  // clamp; stores guarded
  int beg = rowptr[node];
  int m = rowptr[node + 1] - beg;
  float dvc = dinv[node];

  const bf16_t* zb = zq + (size_t)qr * (size_t)N * 16;  // this quarter's array
  size_t base = (size_t)node * 16 + u * 4;

  union U { bf16x4 v; unsigned d[2]; };
  U zs;
  zs.v = *(const bf16x4*)(zb + base);  // self term (already dinv-scaled)
  float a0 = __uint_as_float(zs.d[0] << 16);
  float a1 = __uint_as_float(zs.d[0] & 0xFFFF0000u);
  float a2 = __uint_as_float(zs.d[1] << 16);
  float a3 = __uint_as_float(zs.d[1] & 0xFFFF0000u);

  int full = m & ~3;
  int ev = (full > 0) ? ed4[beg + u] : 0;
  for (int off = 0; off < full; off += 4) {
    int nxt = off + 4;
    int evn = (nxt < full) ? ed4[beg + nxt + u] : 0;  // prefetch next chunk
    int s0 = __shfl(ev, gbase + 0, 64);
    int s1 = __shfl(ev, gbase + 1, 64);
    int s2 = __shfl(ev, gbase + 2, 64);
    int s3 = __shfl(ev, gbase + 3, 64);
    U z0, z1, z2, z3;
    z0.v = *(const bf16x4*)(zb + (size_t)s0 * 16 + u * 4);
    z1.v = *(const bf16x4*)(zb + (size_t)s1 * 16 + u * 4);
    z2.v = *(const bf16x4*)(zb + (size_t)s2 * 16 + u * 4);
    z3.v = *(const bf16x4*)(zb + (size_t)s3 * 16 + u * 4);
    a0 += __uint_as_float(z0.d[0] << 16) + __uint_as_float(z1.d[0] << 16) +
          __uint_as_float(z2.d[0] << 16) + __uint_as_float(z3.d[0] << 16);
    a1 += __uint_as_float(z0.d[0] & 0xFFFF0000u) + __uint_as_float(z1.d[0] & 0xFFFF0000u) +
          __uint_as_float(z2.d[0] & 0xFFFF0000u) + __uint_as_float(z3.d[0] & 0xFFFF0000u);
    a2 += __uint_as_float(z0.d[1] << 16) + __uint_as_float(z1.d[1] << 16) +
          __uint_as_float(z2.d[1] << 16) + __uint_as_float(z3.d[1] << 16);
    a3 += __uint_as_float(z0.d[1] & 0xFFFF0000u) + __uint_as_float(z1.d[1] & 0xFFFF0000u) +
          __uint_as_float(z2.d[1] & 0xFFFF0000u) + __uint_as_float(z3.d[1] & 0xFFFF0000u);
    ev = evn;
  }
  int rem = m - full;
  if (rem > 0) {
    int evr = (u < rem) ? ed4[beg + full + u] : 0;
    for (int j = 0; j < rem; ++j) {
      int src = __shfl(evr, gbase + j, 64);
      U z;
      z.v = *(const bf16x4*)(zb + (size_t)src * 16 + u * 4);
      a0 += __uint_as_float(z.d[0] << 16);
      a1 += __uint_as_float(z.d[0] & 0xFFFF0000u);
      a2 += __uint_as_float(z.d[1] << 16);
      a3 += __uint_as_float(z.d[1] & 0xFFFF0000u);
    }
  }

  float sca = 0.9f * dvc;
  if (LAST) {
    // hf is [N][64] fp32; output zfinal [N][64] fp32
    size_t fo = (size_t)node * 64 + qr * 16 + u * 4;
    f32x4 hv = *(const f32x4*)(hf + fo);
    f32x4 res;
    res.x = sca * a0 + 0.1f * hv.x;
    res.y = sca * a1 + 0.1f * hv.y;
    res.z = sca * a2 + 0.1f * hv.z;
    res.w = sca * a3 + 0.1f * hv.w;
    if (live) *(f32x4*)((float*)zout_ + fo) = res;
  } else {
    U hv;
    hv.v = *(const bf16x4*)(hbq + (size_t)qr * (size_t)N * 16 + base);
    float r0 = dvc * (sca * a0 + 0.1f * __uint_as_float(hv.d[0] << 16));
    float r1 = dvc * (sca * a1 + 0.1f * __uint_as_float(hv.d[0] & 0xFFFF0000u));
    float r2 = dvc * (sca * a2 + 0.1f * __uint_as_float(hv.d[1] << 16));
    float r3 = dvc * (sca * a3 + 0.1f * __uint_as_float(hv.d[1] & 0xFFFF0000u));
    unsigned o0 = (unsigned)f2bf(r0) | (((unsigned)f2bf(r1)) << 16);
    unsigned o1 = (unsigned)f2bf(r2) | (((unsigned)f2bf(r3)) << 16);
    if (live) {
      uint2 o = make_uint2(o0, o1);
      *(uint2*)((bf16_t*)zout_ + (size_t)qr * (size_t)N * 16 + base) = o;
    }
  }
}

// ---------------- launch ----------------

extern "C" void kernel_launch(void* const* d_in, const int* in_sizes, int n_in,
                              void* d_out, int out_size, void* d_ws, size_t ws_size,
                              hipStream_t stream) {
  const float* x = (const float*)d_in[0];
  const int* ei = (const int*)d_in[1];  // int32 per harness contract
  const float* W1 = (const float*)d_in[2];
  const float* b1 = (const float*)d_in[3];
  float* zfinal = (float*)d_out;

  int OUT = in_sizes[3];        // 64
  int IN = in_sizes[2] / OUT;   // 256
  int N = in_sizes[0] / IN;     // 100000
  int E = in_sizes[1] / 2;      // 1600000

  char* ws = (char*)d_ws;
  size_t off = 0;
  auto alloc = [&](size_t bytes) -> char* {
    char* p = ws + off;
    off = (off + bytes + 255) & ~(size_t)255;
    return p;
  };
  int nbuck = (N + 511) >> 9;  // 196
  float* h = (float*)alloc((size_t)N * OUT * 4);        // 25.6 MB [N][64]
  bf16_t* hbq = (bf16_t*)alloc((size_t)N * OUT * 2);    // 12.8 MB [4][N][16]
  bf16_t* zs0q = (bf16_t*)alloc((size_t)N * OUT * 2);   // 12.8 MB [4][N][16]
  bf16_t* z0q = (bf16_t*)alloc((size_t)N * OUT * 2);    // 12.8 MB [4][N][16]
  bf16_t* z1q = (bf16_t*)alloc((size_t)N * OUT * 2);    // 12.8 MB [4][N][16]
  int2* barr = (int2*)alloc((size_t)nbuck * BCAP * 8);  // 25.7 MB
  int* ed4 = (int*)alloc((size_t)E * 4 + 64);           // 6.4 MB
  short* Whp = (short*)alloc(16384 * 2);
  short* Wlp = (short*)alloc(16384 * 2);
  int* rowptr = (int*)alloc((size_t)(N + 1) * 4);
  float* dinv = (float*)alloc((size_t)N * 4);
  int* bcur = (int*)alloc(256 * 4);
  int* bstart = (int*)alloc(256 * 4);
  (void)ws_size;

  hipLaunchKernelGGL(k_initb, dim3(1), dim3(256), 0, stream, bcur, nbuck);
  hipLaunchKernelGGL(k_bucket, dim3((E + TILE - 1) / TILE), dim3(256), 0, stream, ei, E,
                     bcur, barr);
  hipLaunchKernelGGL(k_bscan, dim3(1), dim3(256), 0, stream, bcur, bstart, nbuck, rowptr,
                     N, E);
  hipLaunchKernelGGL(k_finalize, dim3(nbuck), dim3(512), 0, stream, bcur, bstart, barr,
                     rowptr, dinv, ed4, N);
  hipLaunchKernelGGL(k_prep_w, dim3(64), dim3(256), 0, stream, W1, Whp, Wlp);
  hipLaunchKernelGGL(k_gemm_mfma, dim3((N + 127) / 128), dim3(512), 0, stream, x, Whp,
                     Wlp, b1, dinv, h, hbq, zs0q, N);

  // 64-node segments; pairs of segments share an XCD-pair per quarter
  int segs = (N + 63) / 64;        // 1563
  int pairs = (segs + 1) / 2;      // 782
  dim3 pgrid(pairs * 8);           // blockIdx&7 -> XCD -> quarter pair
  const bf16_t* zi = zs0q;
  bf16_t* zb[2] = {z0q, z1q};
  for (int it = 0; it < KITER - 1; ++it) {
    bf16_t* zo = zb[it & 1];
    hipLaunchKernelGGL((k_propq<0>), pgrid, dim3(256), 0, stream, rowptr, ed4, dinv, zi,
                       hbq, h, (void*)zo, N, pairs);
    zi = zo;
  }
  hipLaunchKernelGGL((k_propq<1>), pgrid, dim3(256), 0, stream, rowptr, ed4, dinv, zi,
                     hbq, h, (void*)zfinal, N, pairs);
}

// Round 12
// 426.145 us; speedup vs baseline: 1.2318x; 1.2318x over previous
//
#include <hip/hip_runtime.h>

#define KITER 10
#define TILE 4096
#define BCAP 16384  // bucket staging capacity (expected 8192/bucket, +90 sigma)
typedef unsigned short bf16_t;
typedef __attribute__((ext_vector_type(4))) short bf16x4;
typedef __attribute__((ext_vector_type(8))) short bf16x8;
typedef __attribute__((ext_vector_type(4))) float f32x4;
typedef __attribute__((ext_vector_type(4))) unsigned ui32x4;

__device__ __forceinline__ float bf2f(bf16_t u) {
  union { unsigned u; float f; } cv;
  cv.u = ((unsigned)u) << 16;
  return cv.f;
}
__device__ __forceinline__ bf16_t f2bf(float f) {
  unsigned u = __float_as_uint(f);
  unsigned r = (u + 0x7FFFu + ((u >> 16) & 1u)) >> 16;  // round-nearest-even
  return (bf16_t)r;
}

// ---------------- bucket cursor init: bcur[b] = b*BCAP ----------------
__global__ void k_initb(int* __restrict__ bcur, int nbuck) {
  int i = threadIdx.x;
  if (i < nbuck) bcur[i] = i * BCAP;
}

// ---------------- bucket sort pass A: tile -> per-bucket coalesced runs ------
__global__ __launch_bounds__(256) void k_bucket(const int* __restrict__ ei, int E,
                                                int* __restrict__ bcur,
                                                int2* __restrict__ barr) {
  __shared__ int hist[256];
  __shared__ int scn[256];
  __shared__ int excl[256];
  __shared__ int gb[256];
  __shared__ unsigned char lb[TILE];
  __shared__ int2 stg[TILE];
  int t = threadIdx.x;
  int base = blockIdx.x * TILE;
  hist[t] = 0;
  __syncthreads();
  int s[16], c[16];
#pragma unroll
  for (int i = 0; i < 16; ++i) {
    int e = base + i * 256 + t;
    if (e < E) {
      s[i] = ei[e];
      c[i] = ei[E + e];
      atomicAdd(&hist[c[i] >> 9], 1);
    } else {
      c[i] = -1;
    }
  }
  __syncthreads();
  int h = hist[t];
  scn[t] = h;
  __syncthreads();
  for (int off = 1; off < 256; off <<= 1) {
    int v = (t >= off) ? scn[t - off] : 0;
    __syncthreads();
    scn[t] += v;
    __syncthreads();
  }
  excl[t] = scn[t] - h;
  gb[t] = (h > 0) ? atomicAdd(&bcur[t], h) : 0;
  __syncthreads();
  hist[t] = excl[t];  // reuse as local placement cursor
  __syncthreads();
#pragma unroll
  for (int i = 0; i < 16; ++i) {
    if (c[i] >= 0) {
      int b = c[i] >> 9;
      int p = atomicAdd(&hist[b], 1);
      stg[p] = make_int2(s[i], c[i]);
      lb[p] = (unsigned char)b;
    }
  }
  __syncthreads();
  int cntE = min(TILE, E - base);
#pragma unroll
  for (int i = 0; i < 16; ++i) {
    int p = i * 256 + t;
    if (p < cntE) {
      int b = lb[p];
      barr[gb[b] + (p - excl[b])] = stg[p];
    }
  }
}

// ---------------- bucket-level exclusive prefix (nbuck <= 256), 1 block ------
__global__ void k_bscan(const int* __restrict__ bcur, int* __restrict__ bstart,
                        int nbuck, int* __restrict__ rowptr, int N, int E) {
  __shared__ int s[256];
  int t = threadIdx.x;
  int v = (t < nbuck) ? (bcur[t] - t * BCAP) : 0;
  s[t] = v;
  __syncthreads();
  for (int off = 1; off < 256; off <<= 1) {
    int tv = (t >= off) ? s[t - off] : 0;
    __syncthreads();
    s[t] += tv;
    __syncthreads();
  }
  if (t < nbuck) bstart[t] = s[t] - v;
  if (t == 0) rowptr[N] = E;
}

// ---------------- pass B: bucket -> CSR; also emits rowptr & dinv ------------
__global__ __launch_bounds__(512) void k_finalize(const int* __restrict__ bcur,
                                                  const int* __restrict__ bstart,
                                                  const int2* __restrict__ barr,
                                                  int* __restrict__ rowptr,
                                                  float* __restrict__ dinv,
                                                  int* __restrict__ ed4, int N) {
  __shared__ int cnt[512];
  __shared__ int sbuf[512];
  __shared__ int cur[512];
  int b = blockIdx.x;
  int node0 = b << 9;
  int nn = min(512, N - node0);
  int t = threadIdx.x;
  cnt[t] = 0;
  __syncthreads();
  int m = bcur[b] - b * BCAP;  // edges in this bucket
  int src = b * BCAP;
  int bst = bstart[b];
  for (int i = t; i < m; i += 512) atomicAdd(&cnt[barr[src + i].y - node0], 1);
  __syncthreads();
  int v = cnt[t];
  sbuf[t] = v;
  __syncthreads();
  for (int off = 1; off < 512; off <<= 1) {
    int tv = (t >= off) ? sbuf[t - off] : 0;
    __syncthreads();
    sbuf[t] += tv;
    __syncthreads();
  }
  int excl = sbuf[t] - v;
  if (t < nn) {
    rowptr[node0 + t] = bst + excl;
    dinv[node0 + t] = rsqrtf((float)v + 1.0f);
  }
  cur[t] = bst + excl;
  __syncthreads();
  for (int i = t; i < m; i += 512) {
    int2 q = barr[src + i];
    int slot = atomicAdd(&cur[q.y - node0], 1);
    ed4[slot] = q.x;
  }
}

// ---------------- W pack: split fp32 W into bf16 hi/lo, MFMA B-frag layout ----
__global__ void k_prep_w(const float* __restrict__ W, short* __restrict__ Whp,
                         short* __restrict__ Wlp) {
  int i = blockIdx.x * 256 + threadIdx.x;  // 0..16383
  int j = i & 7;
  int lane = (i >> 3) & 63;
  int cg = (i >> 9) & 3;
  int kc = i >> 11;
  int k = kc * 32 + (lane >> 4) * 8 + j;
  int col = cg * 16 + (lane & 15);
  float w = W[k * 64 + col];
  unsigned u = __float_as_uint(w);
  unsigned hbits = u & 0xFFFF0000u;  // truncate: residual captured exactly by lo
  Whp[i] = (short)(hbits >> 16);
  Wlp[i] = (short)f2bf(w - __uint_as_float(hbits));
}

// ---------------- h = relu(x @ W1 + b1), split-precision bf16 MFMA -----------
// Measured-best R5/R10 configuration (65 us): 512 thr = 8 waves, W hi/lo in
// LDS (64 KB), full x reg prefetch, bias+relu in-reg, C tile staged through
// LDS (reusing W buffer post-compute), fully coalesced full-line writeout.
__global__ __launch_bounds__(512) void k_gemm_mfma(const float* __restrict__ x,
                                                   const short* __restrict__ Whp,
                                                   const short* __restrict__ Wlp,
                                                   const float* __restrict__ b,
                                                   const float* __restrict__ dinv,
                                                   float* __restrict__ h,
                                                   bf16_t* __restrict__ hb,
                                                   bf16_t* __restrict__ zs0, int N) {
  __shared__ __align__(16) char smem[65536];
  short* WhS = (short*)smem;             // 32 KB
  short* WlS = (short*)(smem + 32768);   // 32 KB
  float* Cst = (float*)smem;             // reused post-compute: 128 x 68 floats
  int tid = threadIdx.x;
  for (int i = tid; i < 2048; i += 512) {
    ((int4*)WhS)[i] = ((const int4*)Whp)[i];
    ((int4*)WlS)[i] = ((const int4*)Wlp)[i];
  }
  __syncthreads();
  int wid = tid >> 6;
  int lane = tid & 63;
  int rr = lane & 15;
  int q = lane >> 4;
  long row0 = (long)blockIdx.x * 128 + wid * 16;
  long arow = row0 + rr;
  if (arow > N - 1) arow = N - 1;  // clamp (stores guarded)
  const float* xr = x + arow * 256 + q * 8;

  // prefetch whole row slice: 8 kchunks x 8 floats
  f32x4 xa[8], xb[8];
#pragma unroll
  for (int kc = 0; kc < 8; ++kc) {
    xa[kc] = *(const f32x4*)(xr + kc * 32);
    xb[kc] = *(const f32x4*)(xr + kc * 32 + 4);
  }

  f32x4 acc[4];
#pragma unroll
  for (int cg = 0; cg < 4; ++cg) acc[cg] = (f32x4){0.f, 0.f, 0.f, 0.f};

#pragma unroll
  for (int kc = 0; kc < 8; ++kc) {
    float f[8] = {xa[kc].x, xa[kc].y, xa[kc].z, xa[kc].w,
                  xb[kc].x, xb[kc].y, xb[kc].z, xb[kc].w};
    bf16x8 xh, xl;
#pragma unroll
    for (int j = 0; j < 8; ++j) {
      unsigned u = __float_as_uint(f[j]);
      unsigned hbits = u & 0xFFFF0000u;
      xh[j] = (short)(hbits >> 16);
      xl[j] = (short)f2bf(f[j] - __uint_as_float(hbits));
    }
#pragma unroll
    for (int cg = 0; cg < 4; ++cg) {
      const bf16x8 wh = *(const bf16x8*)&WhS[((kc * 4 + cg) * 64 + lane) * 8];
      const bf16x8 wl = *(const bf16x8*)&WlS[((kc * 4 + cg) * 64 + lane) * 8];
      acc[cg] = __builtin_amdgcn_mfma_f32_16x16x32_bf16(xh, wh, acc[cg], 0, 0, 0);
      acc[cg] = __builtin_amdgcn_mfma_f32_16x16x32_bf16(xl, wh, acc[cg], 0, 0, 0);
      acc[cg] = __builtin_amdgcn_mfma_f32_16x16x32_bf16(xh, wl, acc[cg], 0, 0, 0);
    }
  }

  // -------- epilogue: bias+relu in-reg, stage C tile to LDS (W is dead) -----
  __syncthreads();  // all waves finished reading WhS/WlS
#pragma unroll
  for (int cg = 0; cg < 4; ++cg) {
    float bias = b[cg * 16 + rr];
#pragma unroll
    for (int r = 0; r < 4; ++r) {
      float v = fmaxf(acc[cg][r] + bias, 0.f);
      Cst[(wid * 16 + q * 4 + r) * 68 + cg * 16 + rr] = v;
    }
  }
  __syncthreads();

  // -------- coalesced writeout: thread t -> row t>>2, col quarter t&3 -------
  int lrow = tid >> 2;
  int cq = tid & 3;
  long grow = (long)blockIdx.x * 128 + lrow;
  if (grow < N) {
    union F4U { f32x4 v; float f[4]; };
    const float* cp = &Cst[lrow * 68 + cq * 16];
    F4U w0, w1, w2, w3;
    w0.v = *(const f32x4*)cp;
    w1.v = *(const f32x4*)(cp + 4);
    w2.v = *(const f32x4*)(cp + 8);
    w3.v = *(const f32x4*)(cp + 12);
    size_t ob = (size_t)grow * 64 + cq * 16;
    float* hp = h + ob;
    *(f32x4*)hp = w0.v;
    *(f32x4*)(hp + 4) = w1.v;
    *(f32x4*)(hp + 8) = w2.v;
    *(f32x4*)(hp + 12) = w3.v;
    float dv = dinv[grow];
    uint4 ub, ub2, uz, uz2;
    ub.x = (unsigned)f2bf(w0.f[0]) | ((unsigned)f2bf(w0.f[1]) << 16);
    ub.y = (unsigned)f2bf(w0.f[2]) | ((unsigned)f2bf(w0.f[3]) << 16);
    ub.z = (unsigned)f2bf(w1.f[0]) | ((unsigned)f2bf(w1.f[1]) << 16);
    ub.w = (unsigned)f2bf(w1.f[2]) | ((unsigned)f2bf(w1.f[3]) << 16);
    ub2.x = (unsigned)f2bf(w2.f[0]) | ((unsigned)f2bf(w2.f[1]) << 16);
    ub2.y = (unsigned)f2bf(w2.f[2]) | ((unsigned)f2bf(w2.f[3]) << 16);
    ub2.z = (unsigned)f2bf(w3.f[0]) | ((unsigned)f2bf(w3.f[1]) << 16);
    ub2.w = (unsigned)f2bf(w3.f[2]) | ((unsigned)f2bf(w3.f[3]) << 16);
    uz.x = (unsigned)f2bf(dv * w0.f[0]) | ((unsigned)f2bf(dv * w0.f[1]) << 16);
    uz.y = (unsigned)f2bf(dv * w0.f[2]) | ((unsigned)f2bf(dv * w0.f[3]) << 16);
    uz.z = (unsigned)f2bf(dv * w1.f[0]) | ((unsigned)f2bf(dv * w1.f[1]) << 16);
    uz.w = (unsigned)f2bf(dv * w1.f[2]) | ((unsigned)f2bf(dv * w1.f[3]) << 16);
    uz2.x = (unsigned)f2bf(dv * w2.f[0]) | ((unsigned)f2bf(dv * w2.f[1]) << 16);
    uz2.y = (unsigned)f2bf(dv * w2.f[2]) | ((unsigned)f2bf(dv * w2.f[3]) << 16);
    uz2.z = (unsigned)f2bf(dv * w3.f[0]) | ((unsigned)f2bf(dv * w3.f[1]) << 16);
    uz2.w = (unsigned)f2bf(dv * w3.f[2]) | ((unsigned)f2bf(dv * w3.f[3]) << 16);
    *(uint4*)(hb + ob) = ub;
    *(uint4*)(hb + ob + 8) = ub2;
    *(uint4*)(zs0 + ob) = uz;
    *(uint4*)(zs0 + ob + 8) = uz2;
  }
}

// ---------------- propagation: 8 lanes/node, bf16x8 gathers ------------------
// R10 structure (measured 403.96 total) + NON-TEMPORAL hints on the streaming
// accesses (ed4 reads, hbi/hf reads, z_out stores): these single-use streams
// (~32 MB/iter) wash the 4 MB per-XCD L2 that should hold the zin gather
// working set (12.8 MB, each line re-read ~16x/iter). nt keeps zin resident.
template <int LAST>
__global__ __launch_bounds__(256) void k_prop(const int* __restrict__ rowptr,
                                              const int* __restrict__ ed4,
                                              const float* __restrict__ dinv,
                                              const bf16_t* __restrict__ zin,
                                              const bf16_t* __restrict__ hbi,
                                              const float* __restrict__ hf,
                                              void* __restrict__ zout_, int N) {
  int tid = threadIdx.x;
  int lane = tid & 63;
  int u = lane & 7;       // channel octet: channels u*8 .. u*8+7
  int g = lane >> 3;      // node sub-index within wave (0..7)
  int gbase = lane & 56;  // first lane of this group
  int node = blockIdx.x * 32 + (tid >> 6) * 8 + g;
  bool live = node < N;
  if (!live) node = N - 1;  // clamp; stores guarded
  int beg = rowptr[node];
  int m = rowptr[node + 1] - beg;
  float dvc = dinv[node];
  size_t base = (size_t)node * 64 + u * 8;

  union V { bf16x8 v; unsigned d[4]; };
  V zs;
  zs.v = *(const bf16x8*)(zin + base);  // self term (already dinv-scaled)
  float a0 = __uint_as_float(zs.d[0] << 16);
  float a1 = __uint_as_float(zs.d[0] & 0xFFFF0000u);
  float a2 = __uint_as_float(zs.d[1] << 16);
  float a3 = __uint_as_float(zs.d[1] & 0xFFFF0000u);
  float a4 = __uint_as_float(zs.d[2] << 16);
  float a5 = __uint_as_float(zs.d[2] & 0xFFFF0000u);
  float a6 = __uint_as_float(zs.d[3] << 16);
  float a7 = __uint_as_float(zs.d[3] & 0xFFFF0000u);

  int full = m & ~7;
  int ev = (full > 0) ? __builtin_nontemporal_load(ed4 + beg + u) : 0;
  for (int off = 0; off < full; off += 8) {
    int nxt = off + 8;
    int evn = (nxt < full) ? __builtin_nontemporal_load(ed4 + beg + nxt + u) : 0;
    V z0, z1, z2, z3, z4, z5, z6, z7;
    {
      int s0 = __shfl(ev, gbase + 0, 64);
      int s1 = __shfl(ev, gbase + 1, 64);
      int s2 = __shfl(ev, gbase + 2, 64);
      int s3 = __shfl(ev, gbase + 3, 64);
      int s4 = __shfl(ev, gbase + 4, 64);
      int s5 = __shfl(ev, gbase + 5, 64);
      int s6 = __shfl(ev, gbase + 6, 64);
      int s7 = __shfl(ev, gbase + 7, 64);
      z0.v = *(const bf16x8*)(zin + (size_t)s0 * 64 + u * 8);
      z1.v = *(const bf16x8*)(zin + (size_t)s1 * 64 + u * 8);
      z2.v = *(const bf16x8*)(zin + (size_t)s2 * 64 + u * 8);
      z3.v = *(const bf16x8*)(zin + (size_t)s3 * 64 + u * 8);
      z4.v = *(const bf16x8*)(zin + (size_t)s4 * 64 + u * 8);
      z5.v = *(const bf16x8*)(zin + (size_t)s5 * 64 + u * 8);
      z6.v = *(const bf16x8*)(zin + (size_t)s6 * 64 + u * 8);
      z7.v = *(const bf16x8*)(zin + (size_t)s7 * 64 + u * 8);
    }
#pragma unroll
    for (int j = 0; j < 8; ++j) {
      V* zp;
      switch (j) {
        case 0: zp = &z0; break;
        case 1: zp = &z1; break;
        case 2: zp = &z2; break;
        case 3: zp = &z3; break;
        case 4: zp = &z4; break;
        case 5: zp = &z5; break;
        case 6: zp = &z6; break;
        default: zp = &z7; break;
      }
      a0 += __uint_as_float(zp->d[0] << 16);
      a1 += __uint_as_float(zp->d[0] & 0xFFFF0000u);
      a2 += __uint_as_float(zp->d[1] << 16);
      a3 += __uint_as_float(zp->d[1] & 0xFFFF0000u);
      a4 += __uint_as_float(zp->d[2] << 16);
      a5 += __uint_as_float(zp->d[2] & 0xFFFF0000u);
      a6 += __uint_as_float(zp->d[3] << 16);
      a7 += __uint_as_float(zp->d[3] & 0xFFFF0000u);
    }
    ev = evn;
  }
  int rem = m - full;
  if (rem > 0) {
    int evr = (u < rem) ? __builtin_nontemporal_load(ed4 + beg + full + u) : 0;
    for (int j = 0; j < rem; ++j) {
      int src = __shfl(evr, gbase + j, 64);
      V z;
      z.v = *(const bf16x8*)(zin + (size_t)src * 64 + u * 8);
      a0 += __uint_as_float(z.d[0] << 16);
      a1 += __uint_as_float(z.d[0] & 0xFFFF0000u);
      a2 += __uint_as_float(z.d[1] << 16);
      a3 += __uint_as_float(z.d[1] & 0xFFFF0000u);
      a4 += __uint_as_float(z.d[2] << 16);
      a5 += __uint_as_float(z.d[2] & 0xFFFF0000u);
      a6 += __uint_as_float(z.d[3] << 16);
      a7 += __uint_as_float(z.d[3] & 0xFFFF0000u);
    }
  }

  float sca = 0.9f * dvc;
  if (LAST) {
    const float* hp = hf + base;
    f32x4 h0 = __builtin_nontemporal_load((const f32x4*)hp);
    f32x4 h1 = __builtin_nontemporal_load((const f32x4*)(hp + 4));
    f32x4 r0, r1;
    r0.x = sca * a0 + 0.1f * h0.x;
    r0.y = sca * a1 + 0.1f * h0.y;
    r0.z = sca * a2 + 0.1f * h0.z;
    r0.w = sca * a3 + 0.1f * h0.w;
    r1.x = sca * a4 + 0.1f * h1.x;
    r1.y = sca * a5 + 0.1f * h1.y;
    r1.z = sca * a6 + 0.1f * h1.z;
    r1.w = sca * a7 + 0.1f * h1.w;
    if (live) {
      float* zp = (float*)zout_ + base;
      __builtin_nontemporal_store(r0, (f32x4*)zp);
      __builtin_nontemporal_store(r1, (f32x4*)(zp + 4));
    }
  } else {
    V hv;
    hv.v = __builtin_nontemporal_load((const bf16x8*)(hbi + base));
    float r0 = dvc * (sca * a0 + 0.1f * __uint_as_float(hv.d[0] << 16));
    float r1 = dvc * (sca * a1 + 0.1f * __uint_as_float(hv.d[0] & 0xFFFF0000u));
    float r2 = dvc * (sca * a2 + 0.1f * __uint_as_float(hv.d[1] << 16));
    float r3 = dvc * (sca * a3 + 0.1f * __uint_as_float(hv.d[1] & 0xFFFF0000u));
    float r4 = dvc * (sca * a4 + 0.1f * __uint_as_float(hv.d[2] << 16));
    float r5 = dvc * (sca * a5 + 0.1f * __uint_as_float(hv.d[2] & 0xFFFF0000u));
    float r6 = dvc * (sca * a6 + 0.1f * __uint_as_float(hv.d[3] << 16));
    float r7 = dvc * (sca * a7 + 0.1f * __uint_as_float(hv.d[3] & 0xFFFF0000u));
    ui32x4 o;
    o.x = (unsigned)f2bf(r0) | (((unsigned)f2bf(r1)) << 16);
    o.y = (unsigned)f2bf(r2) | (((unsigned)f2bf(r3)) << 16);
    o.z = (unsigned)f2bf(r4) | (((unsigned)f2bf(r5)) << 16);
    o.w = (unsigned)f2bf(r6) | (((unsigned)f2bf(r7)) << 16);
    if (live)
      __builtin_nontemporal_store(o, (ui32x4*)((bf16_t*)zout_ + base));
  }
}

// ---------------- launch ----------------

extern "C" void kernel_launch(void* const* d_in, const int* in_sizes, int n_in,
                              void* d_out, int out_size, void* d_ws, size_t ws_size,
                              hipStream_t stream) {
  const float* x = (const float*)d_in[0];
  const int* ei = (const int*)d_in[1];  // int32 per harness contract
  const float* W1 = (const float*)d_in[2];
  const float* b1 = (const float*)d_in[3];
  float* zfinal = (float*)d_out;

  int OUT = in_sizes[3];        // 64
  int IN = in_sizes[2] / OUT;   // 256
  int N = in_sizes[0] / IN;     // 100000
  int E = in_sizes[1] / 2;      // 1600000

  char* ws = (char*)d_ws;
  size_t off = 0;
  auto alloc = [&](size_t bytes) -> char* {
    char* p = ws + off;
    off = (off + bytes + 255) & ~(size_t)255;
    return p;
  };
  int nbuck = (N + 511) >> 9;  // 196
  float* h = (float*)alloc((size_t)N * OUT * 4);       // 25.6 MB
  bf16_t* hb = (bf16_t*)alloc((size_t)N * OUT * 2);    // 12.8 MB
  bf16_t* zs0 = (bf16_t*)alloc((size_t)N * OUT * 2);   // 12.8 MB
  bf16_t* z0 = (bf16_t*)alloc((size_t)N * OUT * 2);    // 12.8 MB
  bf16_t* z1 = (bf16_t*)alloc((size_t)N * OUT * 2);    // 12.8 MB
  int2* barr = (int2*)alloc((size_t)nbuck * BCAP * 8); // 25.7 MB
  int* ed4 = (int*)alloc((size_t)E * 4 + 64);          // 6.4 MB
  short* Whp = (short*)alloc(16384 * 2);
  short* Wlp = (short*)alloc(16384 * 2);
  int* rowptr = (int*)alloc((size_t)(N + 1) * 4);
  float* dinv = (float*)alloc((size_t)N * 4);
  int* bcur = (int*)alloc(256 * 4);
  int* bstart = (int*)alloc(256 * 4);
  (void)ws_size;

  hipLaunchKernelGGL(k_initb, dim3(1), dim3(256), 0, stream, bcur, nbuck);
  hipLaunchKernelGGL(k_bucket, dim3((E + TILE - 1) / TILE), dim3(256), 0, stream, ei, E,
                     bcur, barr);
  hipLaunchKernelGGL(k_bscan, dim3(1), dim3(256), 0, stream, bcur, bstart, nbuck, rowptr,
                     N, E);
  hipLaunchKernelGGL(k_finalize, dim3(nbuck), dim3(512), 0, stream, bcur, bstart, barr,
                     rowptr, dinv, ed4, N);
  hipLaunchKernelGGL(k_prep_w, dim3(64), dim3(256), 0, stream, W1, Whp, Wlp);
  hipLaunchKernelGGL(k_gemm_mfma, dim3((N + 127) / 128), dim3(512), 0, stream, x, Whp,
                     Wlp, b1, dinv, h, hb, zs0, N);

  dim3 pgrid((N + 31) / 32);  // 256 threads = 4 waves x 8 nodes = 32 nodes/block
  const bf16_t* zi = zs0;
  bf16_t* zb[2] = {z0, z1};
  for (int it = 0; it < KITER - 1; ++it) {
    bf16_t* zo = zb[it & 1];
    hipLaunchKernelGGL((k_prop<0>), pgrid, dim3(256), 0, stream, rowptr, ed4, dinv, zi,
                       hb, h, (void*)zo, N);
    zi = zo;
  }
  hipLaunchKernelGGL((k_prop<1>), pgrid, dim3(256), 0, stream, rowptr, ed4, dinv, zi, hb,
                     h, (void*)zfinal, N);
}

// Round 13
// 408.399 us; speedup vs baseline: 1.2854x; 1.0435x over previous
//
#include <hip/hip_runtime.h>

#define KITER 10
#define TILE 4096
#define BCAP 16384  // bucket staging capacity (expected 8192/bucket, +90 sigma)
typedef unsigned short bf16_t;
typedef __attribute__((ext_vector_type(4))) short bf16x4;
typedef __attribute__((ext_vector_type(8))) short bf16x8;
typedef __attribute__((ext_vector_type(4))) float f32x4;

__device__ __forceinline__ float bf2f(bf16_t u) {
  union { unsigned u; float f; } cv;
  cv.u = ((unsigned)u) << 16;
  return cv.f;
}
__device__ __forceinline__ bf16_t f2bf(float f) {
  unsigned u = __float_as_uint(f);
  unsigned r = (u + 0x7FFFu + ((u >> 16) & 1u)) >> 16;  // round-nearest-even
  return (bf16_t)r;
}

// ---------------- bucket cursor init: bcur[b] = b*BCAP ----------------
__global__ void k_initb(int* __restrict__ bcur, int nbuck) {
  int i = threadIdx.x;
  if (i < nbuck) bcur[i] = i * BCAP;
}

// ---------------- bucket sort pass A: tile -> per-bucket coalesced runs ------
__global__ __launch_bounds__(256) void k_bucket(const int* __restrict__ ei, int E,
                                                int* __restrict__ bcur,
                                                int2* __restrict__ barr) {
  __shared__ int hist[256];
  __shared__ int scn[256];
  __shared__ int excl[256];
  __shared__ int gb[256];
  __shared__ unsigned char lb[TILE];
  __shared__ int2 stg[TILE];
  int t = threadIdx.x;
  int base = blockIdx.x * TILE;
  hist[t] = 0;
  __syncthreads();
  int s[16], c[16];
#pragma unroll
  for (int i = 0; i < 16; ++i) {
    int e = base + i * 256 + t;
    if (e < E) {
      s[i] = ei[e];
      c[i] = ei[E + e];
      atomicAdd(&hist[c[i] >> 9], 1);
    } else {
      c[i] = -1;
    }
  }
  __syncthreads();
  int h = hist[t];
  scn[t] = h;
  __syncthreads();
  for (int off = 1; off < 256; off <<= 1) {
    int v = (t >= off) ? scn[t - off] : 0;
    __syncthreads();
    scn[t] += v;
    __syncthreads();
  }
  excl[t] = scn[t] - h;
  gb[t] = (h > 0) ? atomicAdd(&bcur[t], h) : 0;
  __syncthreads();
  hist[t] = excl[t];  // reuse as local placement cursor
  __syncthreads();
#pragma unroll
  for (int i = 0; i < 16; ++i) {
    if (c[i] >= 0) {
      int b = c[i] >> 9;
      int p = atomicAdd(&hist[b], 1);
      stg[p] = make_int2(s[i], c[i]);
      lb[p] = (unsigned char)b;
    }
  }
  __syncthreads();
  int cntE = min(TILE, E - base);
#pragma unroll
  for (int i = 0; i < 16; ++i) {
    int p = i * 256 + t;
    if (p < cntE) {
      int b = lb[p];
      barr[gb[b] + (p - excl[b])] = stg[p];
    }
  }
}

// ---------------- bucket-level exclusive prefix (nbuck <= 256), 1 block ------
__global__ void k_bscan(const int* __restrict__ bcur, int* __restrict__ bstart,
                        int nbuck, int* __restrict__ rowptr, int N, int E) {
  __shared__ int s[256];
  int t = threadIdx.x;
  int v = (t < nbuck) ? (bcur[t] - t * BCAP) : 0;
  s[t] = v;
  __syncthreads();
  for (int off = 1; off < 256; off <<= 1) {
    int tv = (t >= off) ? s[t - off] : 0;
    __syncthreads();
    s[t] += tv;
    __syncthreads();
  }
  if (t < nbuck) bstart[t] = s[t] - v;
  if (t == 0) rowptr[N] = E;
}

// ---------------- pass B: bucket -> CSR; also emits rowptr & dinv ------------
__global__ __launch_bounds__(512) void k_finalize(const int* __restrict__ bcur,
                                                  const int* __restrict__ bstart,
                                                  const int2* __restrict__ barr,
                                                  int* __restrict__ rowptr,
                                                  float* __restrict__ dinv,
                                                  int* __restrict__ ed4, int N) {
  __shared__ int cnt[512];
  __shared__ int sbuf[512];
  __shared__ int cur[512];
  int b = blockIdx.x;
  int node0 = b << 9;
  int nn = min(512, N - node0);
  int t = threadIdx.x;
  cnt[t] = 0;
  __syncthreads();
  int m = bcur[b] - b * BCAP;  // edges in this bucket
  int src = b * BCAP;
  int bst = bstart[b];
  for (int i = t; i < m; i += 512) atomicAdd(&cnt[barr[src + i].y - node0], 1);
  __syncthreads();
  int v = cnt[t];
  sbuf[t] = v;
  __syncthreads();
  for (int off = 1; off < 512; off <<= 1) {
    int tv = (t >= off) ? sbuf[t - off] : 0;
    __syncthreads();
    sbuf[t] += tv;
    __syncthreads();
  }
  int excl = sbuf[t] - v;
  if (t < nn) {
    rowptr[node0 + t] = bst + excl;
    dinv[node0 + t] = rsqrtf((float)v + 1.0f);
  }
  cur[t] = bst + excl;
  __syncthreads();
  for (int i = t; i < m; i += 512) {
    int2 q = barr[src + i];
    int slot = atomicAdd(&cur[q.y - node0], 1);
    ed4[slot] = q.x;
  }
}

// ---------------- W pack: split fp32 W into bf16 hi/lo, MFMA B-frag layout ----
__global__ void k_prep_w(const float* __restrict__ W, short* __restrict__ Whp,
                         short* __restrict__ Wlp) {
  int i = blockIdx.x * 256 + threadIdx.x;  // 0..16383
  int j = i & 7;
  int lane = (i >> 3) & 63;
  int cg = (i >> 9) & 3;
  int kc = i >> 11;
  int k = kc * 32 + (lane >> 4) * 8 + j;
  int col = cg * 16 + (lane & 15);
  float w = W[k * 64 + col];
  unsigned u = __float_as_uint(w);
  unsigned hbits = u & 0xFFFF0000u;  // truncate: residual captured exactly by lo
  Whp[i] = (short)(hbits >> 16);
  Wlp[i] = (short)f2bf(w - __uint_as_float(hbits));
}

// ---------------- h = relu(x @ W1 + b1), split-precision bf16 MFMA -----------
// Measured-best R5/R10 configuration (65 us): 512 thr = 8 waves, W hi/lo in
// LDS (64 KB), full x reg prefetch, bias+relu in-reg, C tile staged through
// LDS (reusing W buffer post-compute), fully coalesced full-line writeout.
__global__ __launch_bounds__(512) void k_gemm_mfma(const float* __restrict__ x,
                                                   const short* __restrict__ Whp,
                                                   const short* __restrict__ Wlp,
                                                   const float* __restrict__ b,
                                                   const float* __restrict__ dinv,
                                                   float* __restrict__ h,
                                                   bf16_t* __restrict__ hb,
                                                   bf16_t* __restrict__ zs0, int N) {
  __shared__ __align__(16) char smem[65536];
  short* WhS = (short*)smem;             // 32 KB
  short* WlS = (short*)(smem + 32768);   // 32 KB
  float* Cst = (float*)smem;             // reused post-compute: 128 x 68 floats
  int tid = threadIdx.x;
  for (int i = tid; i < 2048; i += 512) {
    ((int4*)WhS)[i] = ((const int4*)Whp)[i];
    ((int4*)WlS)[i] = ((const int4*)Wlp)[i];
  }
  __syncthreads();
  int wid = tid >> 6;
  int lane = tid & 63;
  int rr = lane & 15;
  int q = lane >> 4;
  long row0 = (long)blockIdx.x * 128 + wid * 16;
  long arow = row0 + rr;
  if (arow > N - 1) arow = N - 1;  // clamp (stores guarded)
  const float* xr = x + arow * 256 + q * 8;

  // prefetch whole row slice: 8 kchunks x 8 floats
  f32x4 xa[8], xb[8];
#pragma unroll
  for (int kc = 0; kc < 8; ++kc) {
    xa[kc] = *(const f32x4*)(xr + kc * 32);
    xb[kc] = *(const f32x4*)(xr + kc * 32 + 4);
  }

  f32x4 acc[4];
#pragma unroll
  for (int cg = 0; cg < 4; ++cg) acc[cg] = (f32x4){0.f, 0.f, 0.f, 0.f};

#pragma unroll
  for (int kc = 0; kc < 8; ++kc) {
    float f[8] = {xa[kc].x, xa[kc].y, xa[kc].z, xa[kc].w,
                  xb[kc].x, xb[kc].y, xb[kc].z, xb[kc].w};
    bf16x8 xh, xl;
#pragma unroll
    for (int j = 0; j < 8; ++j) {
      unsigned u = __float_as_uint(f[j]);
      unsigned hbits = u & 0xFFFF0000u;
      xh[j] = (short)(hbits >> 16);
      xl[j] = (short)f2bf(f[j] - __uint_as_float(hbits));
    }
#pragma unroll
    for (int cg = 0; cg < 4; ++cg) {
      const bf16x8 wh = *(const bf16x8*)&WhS[((kc * 4 + cg) * 64 + lane) * 8];
      const bf16x8 wl = *(const bf16x8*)&WlS[((kc * 4 + cg) * 64 + lane) * 8];
      acc[cg] = __builtin_amdgcn_mfma_f32_16x16x32_bf16(xh, wh, acc[cg], 0, 0, 0);
      acc[cg] = __builtin_amdgcn_mfma_f32_16x16x32_bf16(xl, wh, acc[cg], 0, 0, 0);
      acc[cg] = __builtin_amdgcn_mfma_f32_16x16x32_bf16(xh, wl, acc[cg], 0, 0, 0);
    }
  }

  // -------- epilogue: bias+relu in-reg, stage C tile to LDS (W is dead) -----
  __syncthreads();  // all waves finished reading WhS/WlS
#pragma unroll
  for (int cg = 0; cg < 4; ++cg) {
    float bias = b[cg * 16 + rr];
#pragma unroll
    for (int r = 0; r < 4; ++r) {
      float v = fmaxf(acc[cg][r] + bias, 0.f);
      Cst[(wid * 16 + q * 4 + r) * 68 + cg * 16 + rr] = v;
    }
  }
  __syncthreads();

  // -------- coalesced writeout: thread t -> row t>>2, col quarter t&3 -------
  int lrow = tid >> 2;
  int cq = tid & 3;
  long grow = (long)blockIdx.x * 128 + lrow;
  if (grow < N) {
    union F4U { f32x4 v; float f[4]; };
    const float* cp = &Cst[lrow * 68 + cq * 16];
    F4U w0, w1, w2, w3;
    w0.v = *(const f32x4*)cp;
    w1.v = *(const f32x4*)(cp + 4);
    w2.v = *(const f32x4*)(cp + 8);
    w3.v = *(const f32x4*)(cp + 12);
    size_t ob = (size_t)grow * 64 + cq * 16;
    float* hp = h + ob;
    *(f32x4*)hp = w0.v;
    *(f32x4*)(hp + 4) = w1.v;
    *(f32x4*)(hp + 8) = w2.v;
    *(f32x4*)(hp + 12) = w3.v;
    float dv = dinv[grow];
    uint4 ub, ub2, uz, uz2;
    ub.x = (unsigned)f2bf(w0.f[0]) | ((unsigned)f2bf(w0.f[1]) << 16);
    ub.y = (unsigned)f2bf(w0.f[2]) | ((unsigned)f2bf(w0.f[3]) << 16);
    ub.z = (unsigned)f2bf(w1.f[0]) | ((unsigned)f2bf(w1.f[1]) << 16);
    ub.w = (unsigned)f2bf(w1.f[2]) | ((unsigned)f2bf(w1.f[3]) << 16);
    ub2.x = (unsigned)f2bf(w2.f[0]) | ((unsigned)f2bf(w2.f[1]) << 16);
    ub2.y = (unsigned)f2bf(w2.f[2]) | ((unsigned)f2bf(w2.f[3]) << 16);
    ub2.z = (unsigned)f2bf(w3.f[0]) | ((unsigned)f2bf(w3.f[1]) << 16);
    ub2.w = (unsigned)f2bf(w3.f[2]) | ((unsigned)f2bf(w3.f[3]) << 16);
    uz.x = (unsigned)f2bf(dv * w0.f[0]) | ((unsigned)f2bf(dv * w0.f[1]) << 16);
    uz.y = (unsigned)f2bf(dv * w0.f[2]) | ((unsigned)f2bf(dv * w0.f[3]) << 16);
    uz.z = (unsigned)f2bf(dv * w1.f[0]) | ((unsigned)f2bf(dv * w1.f[1]) << 16);
    uz.w = (unsigned)f2bf(dv * w1.f[2]) | ((unsigned)f2bf(dv * w1.f[3]) << 16);
    uz2.x = (unsigned)f2bf(dv * w2.f[0]) | ((unsigned)f2bf(dv * w2.f[1]) << 16);
    uz2.y = (unsigned)f2bf(dv * w2.f[2]) | ((unsigned)f2bf(dv * w2.f[3]) << 16);
    uz2.z = (unsigned)f2bf(dv * w3.f[0]) | ((unsigned)f2bf(dv * w3.f[1]) << 16);
    uz2.w = (unsigned)f2bf(dv * w3.f[2]) | ((unsigned)f2bf(dv * w3.f[3]) << 16);
    *(uint4*)(hb + ob) = ub;
    *(uint4*)(hb + ob + 8) = ub2;
    *(uint4*)(zs0 + ob) = uz;
    *(uint4*)(zs0 + ob + 8) = uz2;
  }
}

// ---------------- propagation: 8 lanes/node, bf16x8 gathers ------------------
// R10 configuration (measured best, 403.96 us total): ed4 index prefetch
// hides the edge-index L2 latency under the accumulate VALU. Plain (cached)
// loads/stores throughout — nt hints measured null-to-negative (R12).
template <int LAST>
__global__ __launch_bounds__(256) void k_prop(const int* __restrict__ rowptr,
                                              const int* __restrict__ ed4,
                                              const float* __restrict__ dinv,
                                              const bf16_t* __restrict__ zin,
                                              const bf16_t* __restrict__ hbi,
                                              const float* __restrict__ hf,
                                              void* __restrict__ zout_, int N) {
  int tid = threadIdx.x;
  int lane = tid & 63;
  int u = lane & 7;       // channel octet: channels u*8 .. u*8+7
  int g = lane >> 3;      // node sub-index within wave (0..7)
  int gbase = lane & 56;  // first lane of this group
  int node = blockIdx.x * 32 + (tid >> 6) * 8 + g;
  bool live = node < N;
  if (!live) node = N - 1;  // clamp; stores guarded
  int beg = rowptr[node];
  int m = rowptr[node + 1] - beg;
  float dvc = dinv[node];
  size_t base = (size_t)node * 64 + u * 8;

  union V { bf16x8 v; unsigned d[4]; };
  V zs;
  zs.v = *(const bf16x8*)(zin + base);  // self term (already dinv-scaled)
  float a0 = __uint_as_float(zs.d[0] << 16);
  float a1 = __uint_as_float(zs.d[0] & 0xFFFF0000u);
  float a2 = __uint_as_float(zs.d[1] << 16);
  float a3 = __uint_as_float(zs.d[1] & 0xFFFF0000u);
  float a4 = __uint_as_float(zs.d[2] << 16);
  float a5 = __uint_as_float(zs.d[2] & 0xFFFF0000u);
  float a6 = __uint_as_float(zs.d[3] << 16);
  float a7 = __uint_as_float(zs.d[3] & 0xFFFF0000u);

  int full = m & ~7;
  int ev = (full > 0) ? ed4[beg + u] : 0;
  for (int off = 0; off < full; off += 8) {
    int nxt = off + 8;
    int evn = (nxt < full) ? ed4[beg + nxt + u] : 0;  // prefetch next chunk
    V z0, z1, z2, z3, z4, z5, z6, z7;
    {
      int s0 = __shfl(ev, gbase + 0, 64);
      int s1 = __shfl(ev, gbase + 1, 64);
      int s2 = __shfl(ev, gbase + 2, 64);
      int s3 = __shfl(ev, gbase + 3, 64);
      int s4 = __shfl(ev, gbase + 4, 64);
      int s5 = __shfl(ev, gbase + 5, 64);
      int s6 = __shfl(ev, gbase + 6, 64);
      int s7 = __shfl(ev, gbase + 7, 64);
      z0.v = *(const bf16x8*)(zin + (size_t)s0 * 64 + u * 8);
      z1.v = *(const bf16x8*)(zin + (size_t)s1 * 64 + u * 8);
      z2.v = *(const bf16x8*)(zin + (size_t)s2 * 64 + u * 8);
      z3.v = *(const bf16x8*)(zin + (size_t)s3 * 64 + u * 8);
      z4.v = *(const bf16x8*)(zin + (size_t)s4 * 64 + u * 8);
      z5.v = *(const bf16x8*)(zin + (size_t)s5 * 64 + u * 8);
      z6.v = *(const bf16x8*)(zin + (size_t)s6 * 64 + u * 8);
      z7.v = *(const bf16x8*)(zin + (size_t)s7 * 64 + u * 8);
    }
#pragma unroll
    for (int j = 0; j < 8; ++j) {
      V* zp;
      switch (j) {
        case 0: zp = &z0; break;
        case 1: zp = &z1; break;
        case 2: zp = &z2; break;
        case 3: zp = &z3; break;
        case 4: zp = &z4; break;
        case 5: zp = &z5; break;
        case 6: zp = &z6; break;
        default: zp = &z7; break;
      }
      a0 += __uint_as_float(zp->d[0] << 16);
      a1 += __uint_as_float(zp->d[0] & 0xFFFF0000u);
      a2 += __uint_as_float(zp->d[1] << 16);
      a3 += __uint_as_float(zp->d[1] & 0xFFFF0000u);
      a4 += __uint_as_float(zp->d[2] << 16);
      a5 += __uint_as_float(zp->d[2] & 0xFFFF0000u);
      a6 += __uint_as_float(zp->d[3] << 16);
      a7 += __uint_as_float(zp->d[3] & 0xFFFF0000u);
    }
    ev = evn;
  }
  int rem = m - full;
  if (rem > 0) {
    int evr = (u < rem) ? ed4[beg + full + u] : 0;
    for (int j = 0; j < rem; ++j) {
      int src = __shfl(evr, gbase + j, 64);
      V z;
      z.v = *(const bf16x8*)(zin + (size_t)src * 64 + u * 8);
      a0 += __uint_as_float(z.d[0] << 16);
      a1 += __uint_as_float(z.d[0] & 0xFFFF0000u);
      a2 += __uint_as_float(z.d[1] << 16);
      a3 += __uint_as_float(z.d[1] & 0xFFFF0000u);
      a4 += __uint_as_float(z.d[2] << 16);
      a5 += __uint_as_float(z.d[2] & 0xFFFF0000u);
      a6 += __uint_as_float(z.d[3] << 16);
      a7 += __uint_as_float(z.d[3] & 0xFFFF0000u);
    }
  }

  float sca = 0.9f * dvc;
  if (LAST) {
    const float* hp = hf + base;
    f32x4 h0 = *(const f32x4*)hp;
    f32x4 h1 = *(const f32x4*)(hp + 4);
    f32x4 r0, r1;
    r0.x = sca * a0 + 0.1f * h0.x;
    r0.y = sca * a1 + 0.1f * h0.y;
    r0.z = sca * a2 + 0.1f * h0.z;
    r0.w = sca * a3 + 0.1f * h0.w;
    r1.x = sca * a4 + 0.1f * h1.x;
    r1.y = sca * a5 + 0.1f * h1.y;
    r1.z = sca * a6 + 0.1f * h1.z;
    r1.w = sca * a7 + 0.1f * h1.w;
    if (live) {
      float* zp = (float*)zout_ + base;
      *(f32x4*)zp = r0;
      *(f32x4*)(zp + 4) = r1;
    }
  } else {
    V hv;
    hv.v = *(const bf16x8*)(hbi + base);
    float r0 = dvc * (sca * a0 + 0.1f * __uint_as_float(hv.d[0] << 16));
    float r1 = dvc * (sca * a1 + 0.1f * __uint_as_float(hv.d[0] & 0xFFFF0000u));
    float r2 = dvc * (sca * a2 + 0.1f * __uint_as_float(hv.d[1] << 16));
    float r3 = dvc * (sca * a3 + 0.1f * __uint_as_float(hv.d[1] & 0xFFFF0000u));
    float r4 = dvc * (sca * a4 + 0.1f * __uint_as_float(hv.d[2] << 16));
    float r5 = dvc * (sca * a5 + 0.1f * __uint_as_float(hv.d[2] & 0xFFFF0000u));
    float r6 = dvc * (sca * a6 + 0.1f * __uint_as_float(hv.d[3] << 16));
    float r7 = dvc * (sca * a7 + 0.1f * __uint_as_float(hv.d[3] & 0xFFFF0000u));
    uint4 o;
    o.x = (unsigned)f2bf(r0) | (((unsigned)f2bf(r1)) << 16);
    o.y = (unsigned)f2bf(r2) | (((unsigned)f2bf(r3)) << 16);
    o.z = (unsigned)f2bf(r4) | (((unsigned)f2bf(r5)) << 16);
    o.w = (unsigned)f2bf(r6) | (((unsigned)f2bf(r7)) << 16);
    if (live) *(uint4*)((bf16_t*)zout_ + base) = o;
  }
}

// ---------------- launch ----------------

extern "C" void kernel_launch(void* const* d_in, const int* in_sizes, int n_in,
                              void* d_out, int out_size, void* d_ws, size_t ws_size,
                              hipStream_t stream) {
  const float* x = (const float*)d_in[0];
  const int* ei = (const int*)d_in[1];  // int32 per harness contract
  const float* W1 = (const float*)d_in[2];
  const float* b1 = (const float*)d_in[3];
  float* zfinal = (float*)d_out;

  int OUT = in_sizes[3];        // 64
  int IN = in_sizes[2] / OUT;   // 256
  int N = in_sizes[0] / IN;     // 100000
  int E = in_sizes[1] / 2;      // 1600000

  char* ws = (char*)d_ws;
  size_t off = 0;
  auto alloc = [&](size_t bytes) -> char* {
    char* p = ws + off;
    off = (off + bytes + 255) & ~(size_t)255;
    return p;
  };
  int nbuck = (N + 511) >> 9;  // 196
  float* h = (float*)alloc((size_t)N * OUT * 4);       // 25.6 MB
  bf16_t* hb = (bf16_t*)alloc((size_t)N * OUT * 2);    // 12.8 MB
  bf16_t* zs0 = (bf16_t*)alloc((size_t)N * OUT * 2);   // 12.8 MB
  bf16_t* z0 = (bf16_t*)alloc((size_t)N * OUT * 2);    // 12.8 MB
  bf16_t* z1 = (bf16_t*)alloc((size_t)N * OUT * 2);    // 12.8 MB
  int2* barr = (int2*)alloc((size_t)nbuck * BCAP * 8); // 25.7 MB
  int* ed4 = (int*)alloc((size_t)E * 4 + 64);          // 6.4 MB
  short* Whp = (short*)alloc(16384 * 2);
  short* Wlp = (short*)alloc(16384 * 2);
  int* rowptr = (int*)alloc((size_t)(N + 1) * 4);
  float* dinv = (float*)alloc((size_t)N * 4);
  int* bcur = (int*)alloc(256 * 4);
  int* bstart = (int*)alloc(256 * 4);
  (void)ws_size;

  hipLaunchKernelGGL(k_initb, dim3(1), dim3(256), 0, stream, bcur, nbuck);
  hipLaunchKernelGGL(k_bucket, dim3((E + TILE - 1) / TILE), dim3(256), 0, stream, ei, E,
                     bcur, barr);
  hipLaunchKernelGGL(k_bscan, dim3(1), dim3(256), 0, stream, bcur, bstart, nbuck, rowptr,
                     N, E);
  hipLaunchKernelGGL(k_finalize, dim3(nbuck), dim3(512), 0, stream, bcur, bstart, barr,
                     rowptr, dinv, ed4, N);
  hipLaunchKernelGGL(k_prep_w, dim3(64), dim3(256), 0, stream, W1, Whp, Wlp);
  hipLaunchKernelGGL(k_gemm_mfma, dim3((N + 127) / 128), dim3(512), 0, stream, x, Whp,
                     Wlp, b1, dinv, h, hb, zs0, N);

  dim3 pgrid((N + 31) / 32);  // 256 threads = 4 waves x 8 nodes = 32 nodes/block
  const bf16_t* zi = zs0;
  bf16_t* zb[2] = {z0, z1};
  for (int it = 0; it < KITER - 1; ++it) {
    bf16_t* zo = zb[it & 1];
    hipLaunchKernelGGL((k_prop<0>), pgrid, dim3(256), 0, stream, rowptr, ed4, dinv, zi,
                       hb, h, (void*)zo, N);
    zi = zo;
  }
  hipLaunchKernelGGL((k_prop<1>), pgrid, dim3(256), 0, stream, rowptr, ed4, dinv, zi, hb,
                     h, (void*)zfinal, N);
}